// Round 8
// baseline (300.618 us; speedup 1.0000x reference)
//
#include <hip/hip_runtime.h>

#define NPTS 12288
#define DIMS 8
#define EPS2 0.25f
#define MINS 5
#define ROWS 2
#define TI   (256 * ROWS)      // 512 rows per adj block
#define SUBT 256               // j-subtile staged in LDS
#define NJB  24
#define JCHUNK (NPTS / NJB)    // 512 bits = 16 words = exactly one 64B line/row
#define NIBD (NPTS / TI)       // 24
#define NIB1 (NPTS / 256)      // 48
#define NW   (NPTS / 32)       // 384 words per adjacency row
#define WCH  (JCHUNK / 32)     // 16 words per j-chunk
#define SENT NPTS
#define RMAX 512               // max contracted labels (R~120 measured OK)
#define W    (RMAX / 32)       // 16 words per contracted-bitmap row
#define BIGL 0x3fffffff
#define FT   128               // threads for border kernel
#define FB   256               // threads for fillbm
#define FBGRID 256             // blocks for fillbm -> 1024 waves

// single distance-computation site (bit-exact vs reference formula)
__device__ __forceinline__ float dist2(const float* xi, const float4& a, const float4& b,
                                       float sqi, float sqj) {
  float dot = 0.f;
  dot = fmaf(xi[0], a.x, dot); dot = fmaf(xi[1], a.y, dot);
  dot = fmaf(xi[2], a.z, dot); dot = fmaf(xi[3], a.w, dot);
  dot = fmaf(xi[4], b.x, dot); dot = fmaf(xi[5], b.y, dot);
  dot = fmaf(xi[6], b.z, dot); dot = fmaf(xi[7], b.w, dot);
  return (sqi + sqj) - 2.0f * dot;
}

// ---------------- kernels ----------------

// the ONLY N^2 distance pass: bits accumulate in registers (16 words = one
// full 64B line per row-chunk), single 4x dwordx4 burst store at the end.
__global__ __launch_bounds__(256) void k_adj(const float* __restrict__ X,
                                             unsigned int* __restrict__ adj) {
  __shared__ float4 xs[SUBT][2];
  __shared__ float sqs[SUBT];
  int t = threadIdx.x;
  int i0 = blockIdx.x * TI + t, i1 = i0 + 256;
  float xi0[DIMS], xi1[DIMS];
#pragma unroll
  for (int d = 0; d < DIMS; d++) { xi0[d] = X[i0 * DIMS + d]; xi1[d] = X[i1 * DIMS + d]; }
  float sq0 = 0.f, sq1 = 0.f;
#pragma unroll
  for (int d = 0; d < DIMS; d++) { sq0 = fmaf(xi0[d], xi0[d], sq0); sq1 = fmaf(xi1[d], xi1[d], sq1); }
  int j0 = blockIdx.y * JCHUNK;
  unsigned int w0[WCH], w1[WCH];               // 16+16 words in registers
#pragma unroll
  for (int js = 0; js < JCHUNK; js += SUBT) {  // 2 iterations, fully unrolled
    __syncthreads();
    {
      int j = j0 + js + t;
      float4 a = ((const float4*)X)[j * 2];
      float4 b = ((const float4*)X)[j * 2 + 1];
      xs[t][0] = a; xs[t][1] = b;
      float s = 0.f;
      s = fmaf(a.x, a.x, s); s = fmaf(a.y, a.y, s); s = fmaf(a.z, a.z, s); s = fmaf(a.w, a.w, s);
      s = fmaf(b.x, b.x, s); s = fmaf(b.y, b.y, s); s = fmaf(b.z, b.z, s); s = fmaf(b.w, b.w, s);
      sqs[t] = s;
    }
    __syncthreads();
#pragma unroll
    for (int w = 0; w < SUBT / 32; w++) {      // 8 words per subtile
      unsigned int b0 = 0u, b1 = 0u;
#pragma unroll
      for (int bit = 0; bit < 32; bit++) {
        int jj = (w << 5) + bit;
        float4 xa = xs[jj][0], xb = xs[jj][1];
        float sj = sqs[jj];
        b0 |= (dist2(xi0, xa, xb, sq0, sj) <= EPS2) ? (1u << bit) : 0u;
        b1 |= (dist2(xi1, xa, xb, sq1, sj) <= EPS2) ? (1u << bit) : 0u;
      }
      w0[(js >> 5) + w] = b0;
      w1[(js >> 5) + w] = b1;
    }
  }
  // full-line burst stores: 4 consecutive dwordx4 per row
  uint4* r0 = (uint4*)(adj + (size_t)i0 * NW + blockIdx.y * WCH);
  uint4* r1 = (uint4*)(adj + (size_t)i1 * NW + blockIdx.y * WCH);
#pragma unroll
  for (int q = 0; q < WCH / 4; q++)
    r0[q] = make_uint4(w0[4 * q], w0[4 * q + 1], w0[4 * q + 2], w0[4 * q + 3]);
#pragma unroll
  for (int q = 0; q < WCH / 4; q++)
    r1[q] = make_uint4(w1[4 * q], w1[4 * q + 1], w1[4 * q + 2], w1[4 * q + 3]);
}

// density = popcount(row); core bitmap via ballot; block 0 zeroes bm+bcount
__global__ __launch_bounds__(256) void k_post(const unsigned int* __restrict__ adj,
                                              int* __restrict__ density,
                                              unsigned long long* __restrict__ corebm,
                                              unsigned int* __restrict__ bm) {
  int t = threadIdx.x;
  if (blockIdx.x == 0) {
#pragma unroll
    for (int q = 0; q < RMAX * W / 256; q++) bm[t + q * 256] = 0u;
  }
  int i = blockIdx.x * 256 + t;
  const uint4* row = (const uint4*)(adj + (size_t)i * NW);
  int s = 0;
#pragma unroll 8
  for (int q = 0; q < NW / 4; q++) {
    uint4 v = row[q];
    s += __popc(v.x) + __popc(v.y) + __popc(v.z) + __popc(v.w);
  }
  density[i] = s;
  unsigned long long m = __ballot(s >= MINS);
  if ((t & 63) == 0) corebm[i >> 6] = m;
}

// hook[i] = min(i, first set bit of adj[i] & core) -- no atomics
__global__ __launch_bounds__(256) void k_hookbm(const unsigned int* __restrict__ adj,
                                                const unsigned int* __restrict__ cb32,
                                                int* __restrict__ hook) {
  __shared__ unsigned int cb[NW];
  int t = threadIdx.x;
  for (int w = t; w < NW; w += 256) cb[w] = cb32[w];
  __syncthreads();
  int i = blockIdx.x * 256 + t;
  const unsigned int* row = adj + (size_t)i * NW;
  int m = i;
  for (int w = 0; w < NW; w++) {
    unsigned int x = row[w] & cb[w];
    if (x) { m = min(m, (w << 5) + __ffs(x) - 1); break; }
  }
  hook[i] = m;
}

// chase the static hook forest (read-only, strictly decreasing => acyclic)
__global__ __launch_bounds__(256) void k_compress(const int* __restrict__ density,
                                                  const int* __restrict__ hook,
                                                  int* __restrict__ L0) {
  int i = blockIdx.x * blockDim.x + threadIdx.x;
  if (i >= NPTS) return;
  if (density[i] >= MINS) {
    int v = i;
    int h = hook[v];
    while (h != v) { v = h; h = hook[v]; }
    L0[i] = v;
  } else {
    L0[i] = i;
  }
}

// root ranks in LDS + labL in one pass; 1024 threads for latency overlap.
__global__ __launch_bounds__(1024) void k_rid(const int* __restrict__ density,
                                              const int* __restrict__ L0,
                                              int* __restrict__ Rptr,
                                              int* __restrict__ labL,
                                              int* __restrict__ bcount) {
  __shared__ unsigned short ridS[NPTS];   // 24 KB: rank of each root index
  __shared__ int wsum[16];
  int t = threadIdx.x;
  int lane = t & 63, wid = t >> 6;
  const int SEG = NPTS / 1024;  // 12
  int base = t * SEG;
  int flags = 0;
  int s = 0;
#pragma unroll
  for (int k = 0; k < SEG; k++) {
    int i = base + k;
    int f = (density[i] >= MINS && L0[i] == i) ? 1 : 0;
    flags |= f << k;
    s += f;
  }
  int segsum = s;
#pragma unroll
  for (int off = 1; off < 64; off <<= 1) {
    int n = __shfl_up(s, off, 64);
    if (lane >= off) s += n;
  }
  if (lane == 63) wsum[wid] = s;
  __syncthreads();
  int woff = 0;
  for (int w = 0; w < wid; w++) woff += wsum[w];
  int run = woff + s - segsum;
#pragma unroll
  for (int k = 0; k < SEG; k++) {
    ridS[base + k] = (unsigned short)run;
    run += (flags >> k) & 1;
  }
  if (t == 1023) *Rptr = run;
  if (t == 0) *bcount = 0;
  __syncthreads();
#pragma unroll
  for (int k = 0; k < SEG; k++) {
    int i = base + k;
    labL[i] = (density[i] >= MINS) ? min((int)ridS[L0[i]], RMAX - 1) : -1;
  }
}

// crossing-label edges -> contracted adjacency.
// Wave-per-row; labels from LDS; hot atomics in LDS; batched merge at end.
__global__ __launch_bounds__(FB) void k_fillbm(const unsigned int* __restrict__ adj,
                                               const unsigned int* __restrict__ cb32,
                                               const int* __restrict__ labL,
                                               unsigned int* __restrict__ bm) {
  __shared__ unsigned int bmL[RMAX * W];       // 32 KB private bitmap
  __shared__ unsigned short labS[NPTS];        // 24 KB labels (+1, 0 = non-core)
  __shared__ unsigned int cb[NW];              // 1.5 KB core bitmap
  int t = threadIdx.x;
  for (int q = t; q < RMAX * W; q += FB) bmL[q] = 0u;
  for (int q = t; q < NPTS; q += FB) labS[q] = (unsigned short)(labL[q] + 1);
  for (int w = t; w < NW; w += FB) cb[w] = cb32[w];
  __syncthreads();
  int lane = t & 63, wv = t >> 6;              // 4 waves per block
  int gw = blockIdx.x * 4 + wv;                // global wave id 0..1023
  for (int i = gw; i < NPTS; i += 4 * FBGRID) {
    int a0 = (int)labS[i] - 1;
    if (a0 < 0) continue;                      // wave-uniform
    const unsigned int* row = adj + (size_t)i * NW;
    for (int w = lane; w < NW; w += 64) {
      unsigned int x = row[w] & cb[w];
      while (x) {
        int b = __ffs(x) - 1; x &= x - 1;
        int lj = (int)labS[(w << 5) + b] - 1;
        if (lj != a0) {
          atomicOr(&bmL[a0 * W + (lj >> 5)], 1u << (lj & 31));
          atomicOr(&bmL[lj * W + (a0 >> 5)], 1u << (a0 & 31));
        }
      }
    }
  }
  __syncthreads();
  for (int q = t; q < RMAX * W; q += FB) {
    unsigned int v = bmL[q];
    if (v) atomicOr(&bm[q], v);
  }
}

// connected components of the contracted graph (single block, LDS) + rank ids
__global__ __launch_bounds__(RMAX) void k_cc(const unsigned int* __restrict__ bm,
                                             const int* __restrict__ Rptr,
                                             int* __restrict__ clab) {
  __shared__ int lbl[RMAX];
  __shared__ int mn[RMAX];
  __shared__ int chg, cmp;
  int a = threadIdx.x;
  int R = *Rptr; if (R > RMAX) R = RMAX;
  lbl[a] = a;
  __syncthreads();
  while (true) {
    int m = lbl[a];
    if (a < R) {
      const unsigned int* row = bm + a * W;
#pragma unroll
      for (int w = 0; w < W; w++) {
        unsigned int bits = row[w];
        while (bits) {
          int b = __ffs(bits) - 1;
          bits &= bits - 1;
          m = min(m, lbl[(w << 5) + b]);
        }
      }
    }
    mn[a] = m;
    if (a == 0) chg = 0;
    __syncthreads();
    int l = lbl[a];
    if (m < l) { atomicMin(&lbl[l], m); atomicMin(&lbl[a], m); chg = 1; }
    __syncthreads();
    while (true) {
      if (a == 0) cmp = 0;
      __syncthreads();
      int nl = lbl[lbl[a]];
      __syncthreads();
      if (nl < lbl[a]) { lbl[a] = nl; cmp = 1; }
      __syncthreads();
      if (!cmp) break;
    }
    if (!chg) break;
    __syncthreads();
  }
  int flag = (a < R && lbl[a] == a) ? 1 : 0;
  mn[a] = flag;
  __syncthreads();
  for (int off = 1; off < RMAX; off <<= 1) {
    int v = mn[a];
    int add = (a >= off) ? mn[a - off] : 0;
    __syncthreads();
    mn[a] = v + add;
    __syncthreads();
  }
  clab[a] = mn[lbl[a]] - 1;
}

// per-point labels; collect border (non-core) points into a compact list
__global__ __launch_bounds__(256) void k_labels(const int* __restrict__ labL,
                                                const int* __restrict__ clab,
                                                int* __restrict__ labArr,
                                                int* __restrict__ blist,
                                                int* __restrict__ bcount,
                                                float* __restrict__ out) {
  int i = blockIdx.x * blockDim.x + threadIdx.x;
  if (i >= NPTS) return;
  int a = labL[i];
  if (a >= 0) {
    int lab = clab[a];
    labArr[i] = lab;
    out[i] = (float)lab;
  } else {
    labArr[i] = BIGL;
    out[i] = -1.0f;
    int pos = atomicAdd(bcount, 1);
    blist[pos] = i;
  }
}

// one block per border point: min cluster id over core neighbors (bitmap scan)
__global__ __launch_bounds__(FT) void k_border(const unsigned int* __restrict__ adj,
                                               const unsigned int* __restrict__ cb32,
                                               const int* __restrict__ labArr,
                                               const int* __restrict__ blist,
                                               const int* __restrict__ bcount,
                                               float* __restrict__ out) {
  __shared__ unsigned int cb[NW];
  __shared__ int wm[FT / 64];
  int t = threadIdx.x;
  for (int w = t; w < NW; w += FT) cb[w] = cb32[w];
  __syncthreads();
  int count = *bcount;
  for (int k = blockIdx.x; k < count; k += gridDim.x) {
    int p = blist[k];
    const unsigned int* row = adj + (size_t)p * NW;
    int m = BIGL;
    for (int w = t; w < NW; w += FT) {
      unsigned int x = row[w] & cb[w];
      while (x) {
        int b = __ffs(x) - 1; x &= x - 1;
        m = min(m, labArr[(w << 5) + b]);
      }
    }
#pragma unroll
    for (int off = 32; off >= 1; off >>= 1) m = min(m, __shfl_xor(m, off, 64));
    if ((t & 63) == 0) wm[t >> 6] = m;
    __syncthreads();
    if (t == 0) {
      int mm = min(wm[0], wm[1]);
      out[p] = (mm < BIGL) ? (float)mm : -1.0f;
    }
    __syncthreads();
  }
}

// ---------------- launch ----------------

extern "C" void kernel_launch(void* const* d_in, const int* in_sizes, int n_in,
                              void* d_out, int out_size, void* d_ws, size_t ws_size,
                              hipStream_t stream) {
  const float* X = (const float*)d_in[0];
  float* out = (float*)d_out;

  char* ws = (char*)d_ws;
  unsigned int* adj = (unsigned int*)ws;                     // 18,874,368 B
  size_t off = (size_t)NPTS * NW * 4;
  int* density = (int*)(ws + off);           off += 4 * NPTS;
  int* hook    = (int*)(ws + off);           off += 4 * NPTS;
  int* L0      = (int*)(ws + off);           off += 4 * NPTS;   // -> labArr
  int* labL    = (int*)(ws + off);           off += 4 * NPTS;
  int* blist   = (int*)(ws + off);           off += 4 * NPTS;
  unsigned long long* corebm = (unsigned long long*)(ws + off); off += 2048;
  unsigned int* bm  = (unsigned int*)(ws + off); off += 4 * RMAX * W;
  int* clab    = (int*)(ws + off);           off += 4 * RMAX;
  int* Rptr    = (int*)(ws + off);
  int* bcount  = Rptr + 1;
  int* labArr  = L0;   // L0 dead after k_rid

  dim3 gridA(NIBD, NJB);

  k_adj<<<gridA, 256, 0, stream>>>(X, adj);
  k_post<<<NIB1, 256, 0, stream>>>(adj, density, corebm, bm);
  k_hookbm<<<NIB1, 256, 0, stream>>>(adj, (const unsigned int*)corebm, hook);
  k_compress<<<NIB1, 256, 0, stream>>>(density, hook, L0);
  k_rid<<<1, 1024, 0, stream>>>(density, L0, Rptr, labL, bcount);
  k_fillbm<<<FBGRID, FB, 0, stream>>>(adj, (const unsigned int*)corebm, labL, bm);
  k_cc<<<1, RMAX, 0, stream>>>(bm, Rptr, clab);
  k_labels<<<NIB1, 256, 0, stream>>>(labL, clab, labArr, blist, bcount, out);
  k_border<<<256, FT, 0, stream>>>(adj, (const unsigned int*)corebm, labArr, blist, bcount, out);
}

// Round 9
// 240.304 us; speedup vs baseline: 1.2510x; 1.2510x over previous
//
#include <hip/hip_runtime.h>

#define NPTS 12288
#define DIMS 8
#define EPS2 0.25f
#define MINS 5
#define NIB1 (NPTS / 256)      // 48
#define NW   (NPTS / 32)       // 384 words per adjacency row
#define SENT NPTS
#define RMAX 512               // max contracted labels (R~120 measured OK)
#define W    (RMAX / 32)       // 16 words per contracted-bitmap row
#define BIGL 0x3fffffff
#define FT   128               // threads for border kernel
#define FB   256               // threads for fillbm
#define FBGRID 256             // blocks for fillbm -> 1024 waves

// k_adj geometry: 128 thr x 4 rows = 512 rows/block; j-chunk 256 = 8 words = 32B
#define ATHR 128
#define AROWS 4
#define ATI  (ATHR * AROWS)    // 512
#define ANIB (NPTS / ATI)      // 24
#define ANJB 48
#define AJC  (NPTS / ANJB)     // 256
#define AWCH (AJC / 32)        // 8

// single distance-computation site (bit-exact vs reference formula)
__device__ __forceinline__ float dist2(const float* xi, const float4& a, const float4& b,
                                       float sqi, float sqj) {
  float dot = 0.f;
  dot = fmaf(xi[0], a.x, dot); dot = fmaf(xi[1], a.y, dot);
  dot = fmaf(xi[2], a.z, dot); dot = fmaf(xi[3], a.w, dot);
  dot = fmaf(xi[4], b.x, dot); dot = fmaf(xi[5], b.y, dot);
  dot = fmaf(xi[6], b.z, dot); dot = fmaf(xi[7], b.w, dot);
  return (sqi + sqj) - 2.0f * dot;
}

// ---------------- kernels ----------------

// the ONLY N^2 distance pass. 4 rows/thread (amortizes LDS reads 4x),
// registers hold 8 words/row (w-loop unrolled: constant indices), bit loop
// unroll-4 to keep code ~2K inst. 32B burst store/row + fused density.
__global__ __launch_bounds__(ATHR) void k_adj(const float* __restrict__ X,
                                              unsigned int* __restrict__ adj,
                                              int* __restrict__ density) {
  __shared__ float4 xs[AJC][2];
  __shared__ float sqs[AJC];
  int t = threadIdx.x;
  int j0 = blockIdx.y * AJC;
  for (int s = t; s < AJC; s += ATHR) {
    int j = j0 + s;
    float4 a = ((const float4*)X)[j * 2];
    float4 b = ((const float4*)X)[j * 2 + 1];
    xs[s][0] = a; xs[s][1] = b;
    float sv = 0.f;
    sv = fmaf(a.x, a.x, sv); sv = fmaf(a.y, a.y, sv); sv = fmaf(a.z, a.z, sv); sv = fmaf(a.w, a.w, sv);
    sv = fmaf(b.x, b.x, sv); sv = fmaf(b.y, b.y, sv); sv = fmaf(b.z, b.z, sv); sv = fmaf(b.w, b.w, sv);
    sqs[s] = sv;
  }
  int ib = blockIdx.x * ATI + t;     // rows: ib + r*ATHR
  float xi[AROWS][DIMS];
  float sqi[AROWS];
#pragma unroll
  for (int r = 0; r < AROWS; r++) {
    int i = ib + r * ATHR;
#pragma unroll
    for (int d = 0; d < DIMS; d++) xi[r][d] = X[i * DIMS + d];
    float sv = 0.f;
#pragma unroll
    for (int d = 0; d < DIMS; d++) sv = fmaf(xi[r][d], xi[r][d], sv);
    sqi[r] = sv;
  }
  __syncthreads();
  unsigned int acc[AROWS][AWCH];
#pragma unroll
  for (int w = 0; w < AWCH; w++) {   // unrolled: acc indices constant
    unsigned int b0 = 0u, b1 = 0u, b2 = 0u, b3 = 0u;
#pragma unroll 4
    for (int bit = 0; bit < 32; bit++) {
      int jj = (w << 5) + bit;
      float4 xa = xs[jj][0], xb = xs[jj][1];
      float sj = sqs[jj];
      unsigned int m = 1u << bit;
      if (dist2(xi[0], xa, xb, sqi[0], sj) <= EPS2) b0 |= m;
      if (dist2(xi[1], xa, xb, sqi[1], sj) <= EPS2) b1 |= m;
      if (dist2(xi[2], xa, xb, sqi[2], sj) <= EPS2) b2 |= m;
      if (dist2(xi[3], xa, xb, sqi[3], sj) <= EPS2) b3 |= m;
    }
    acc[0][w] = b0; acc[1][w] = b1; acc[2][w] = b2; acc[3][w] = b3;
  }
#pragma unroll
  for (int r = 0; r < AROWS; r++) {
    int i = ib + r * ATHR;
    uint4* dst = (uint4*)(adj + (size_t)i * NW + blockIdx.y * AWCH);
    dst[0] = make_uint4(acc[r][0], acc[r][1], acc[r][2], acc[r][3]);
    dst[1] = make_uint4(acc[r][4], acc[r][5], acc[r][6], acc[r][7]);
    int pc = 0;
#pragma unroll
    for (int w = 0; w < AWCH; w++) pc += __popc(acc[r][w]);
    atomicAdd(&density[i], pc);
  }
}

// corebm via ballot; block 0 zeroes the contracted bitmap
__global__ __launch_bounds__(256) void k_core(const int* __restrict__ density,
                                              unsigned long long* __restrict__ corebm,
                                              unsigned int* __restrict__ bm) {
  int t = threadIdx.x;
  if (blockIdx.x == 0) {
#pragma unroll
    for (int q = 0; q < RMAX * W / 256; q++) bm[t + q * 256] = 0u;
  }
  int i = blockIdx.x * 256 + t;
  unsigned long long m = __ballot(density[i] >= MINS);
  if ((t & 63) == 0) corebm[i >> 6] = m;
}

// hook[i] = min(i, first set bit of adj[i] & core) -- no atomics
__global__ __launch_bounds__(256) void k_hookbm(const unsigned int* __restrict__ adj,
                                                const unsigned int* __restrict__ cb32,
                                                int* __restrict__ hook) {
  __shared__ unsigned int cb[NW];
  int t = threadIdx.x;
  for (int w = t; w < NW; w += 256) cb[w] = cb32[w];
  __syncthreads();
  int i = blockIdx.x * 256 + t;
  const unsigned int* row = adj + (size_t)i * NW;
  int m = i;
  for (int w = 0; w < NW; w++) {
    unsigned int x = row[w] & cb[w];
    if (x) { m = min(m, (w << 5) + __ffs(x) - 1); break; }
  }
  hook[i] = m;
}

// chase the static hook forest (read-only, strictly decreasing => acyclic)
__global__ __launch_bounds__(256) void k_compress(const int* __restrict__ density,
                                                  const int* __restrict__ hook,
                                                  int* __restrict__ L0) {
  int i = blockIdx.x * blockDim.x + threadIdx.x;
  if (i >= NPTS) return;
  if (density[i] >= MINS) {
    int v = i;
    int h = hook[v];
    while (h != v) { v = h; h = hook[v]; }
    L0[i] = v;
  } else {
    L0[i] = i;
  }
}

// root ranks in LDS + labL in one pass; 1024 threads for latency overlap.
__global__ __launch_bounds__(1024) void k_rid(const int* __restrict__ density,
                                              const int* __restrict__ L0,
                                              int* __restrict__ Rptr,
                                              int* __restrict__ labL,
                                              int* __restrict__ bcount) {
  __shared__ unsigned short ridS[NPTS];   // 24 KB: rank of each root index
  __shared__ int wsum[16];
  int t = threadIdx.x;
  int lane = t & 63, wid = t >> 6;
  const int SEG = NPTS / 1024;  // 12
  int base = t * SEG;
  int flags = 0;
  int s = 0;
#pragma unroll
  for (int k = 0; k < SEG; k++) {
    int i = base + k;
    int f = (density[i] >= MINS && L0[i] == i) ? 1 : 0;
    flags |= f << k;
    s += f;
  }
  int segsum = s;
#pragma unroll
  for (int off = 1; off < 64; off <<= 1) {
    int n = __shfl_up(s, off, 64);
    if (lane >= off) s += n;
  }
  if (lane == 63) wsum[wid] = s;
  __syncthreads();
  int woff = 0;
  for (int w = 0; w < wid; w++) woff += wsum[w];
  int run = woff + s - segsum;
#pragma unroll
  for (int k = 0; k < SEG; k++) {
    ridS[base + k] = (unsigned short)run;
    run += (flags >> k) & 1;
  }
  if (t == 1023) *Rptr = run;
  if (t == 0) *bcount = 0;
  __syncthreads();
#pragma unroll
  for (int k = 0; k < SEG; k++) {
    int i = base + k;
    labL[i] = (density[i] >= MINS) ? min((int)ridS[L0[i]], RMAX - 1) : -1;
  }
}

// crossing-label edges -> contracted adjacency. Wave-per-row, j>i only
// (each edge once); labels from LDS; hot atomics in LDS; batched merge.
__global__ __launch_bounds__(FB) void k_fillbm(const unsigned int* __restrict__ adj,
                                               const unsigned int* __restrict__ cb32,
                                               const int* __restrict__ labL,
                                               unsigned int* __restrict__ bm) {
  __shared__ unsigned int bmL[RMAX * W];       // 32 KB private bitmap
  __shared__ unsigned short labS[NPTS];        // 24 KB labels (+1, 0 = non-core)
  __shared__ unsigned int cb[NW];              // 1.5 KB core bitmap
  int t = threadIdx.x;
  for (int q = t; q < RMAX * W; q += FB) bmL[q] = 0u;
  for (int q = t; q < NPTS; q += FB) labS[q] = (unsigned short)(labL[q] + 1);
  for (int w = t; w < NW; w += FB) cb[w] = cb32[w];
  __syncthreads();
  int lane = t & 63, wv = t >> 6;              // 4 waves per block
  int gw = blockIdx.x * 4 + wv;                // global wave id 0..1023
  for (int i = gw; i < NPTS; i += 4 * FBGRID) {
    int a0 = (int)labS[i] - 1;
    if (a0 < 0) continue;                      // wave-uniform
    const unsigned int* row = adj + (size_t)i * NW;
    int wi = i >> 5;
    for (int w = wi + lane; w < NW; w += 64) {
      unsigned int x = row[w] & cb[w];
      if (w == wi) x &= (0xFFFFFFFEu << (i & 31));   // bits strictly > i
      while (x) {
        int b = __ffs(x) - 1; x &= x - 1;
        int lj = (int)labS[(w << 5) + b] - 1;
        if (lj != a0) {
          atomicOr(&bmL[a0 * W + (lj >> 5)], 1u << (lj & 31));
          atomicOr(&bmL[lj * W + (a0 >> 5)], 1u << (a0 & 31));
        }
      }
    }
  }
  __syncthreads();
  for (int q = t; q < RMAX * W; q += FB) {
    unsigned int v = bmL[q];
    if (v) atomicOr(&bm[q], v);
  }
}

// connected components of the contracted graph (single block, LDS) + rank ids
__global__ __launch_bounds__(RMAX) void k_cc(const unsigned int* __restrict__ bm,
                                             const int* __restrict__ Rptr,
                                             int* __restrict__ clab) {
  __shared__ int lbl[RMAX];
  __shared__ int mn[RMAX];
  __shared__ int chg, cmp;
  int a = threadIdx.x;
  int R = *Rptr; if (R > RMAX) R = RMAX;
  lbl[a] = a;
  __syncthreads();
  while (true) {
    int m = lbl[a];
    if (a < R) {
      const unsigned int* row = bm + a * W;
#pragma unroll
      for (int w = 0; w < W; w++) {
        unsigned int bits = row[w];
        while (bits) {
          int b = __ffs(bits) - 1;
          bits &= bits - 1;
          m = min(m, lbl[(w << 5) + b]);
        }
      }
    }
    mn[a] = m;
    if (a == 0) chg = 0;
    __syncthreads();
    int l = lbl[a];
    if (m < l) { atomicMin(&lbl[l], m); atomicMin(&lbl[a], m); chg = 1; }
    __syncthreads();
    while (true) {
      if (a == 0) cmp = 0;
      __syncthreads();
      int nl = lbl[lbl[a]];
      __syncthreads();
      if (nl < lbl[a]) { lbl[a] = nl; cmp = 1; }
      __syncthreads();
      if (!cmp) break;
    }
    if (!chg) break;
    __syncthreads();
  }
  int flag = (a < R && lbl[a] == a) ? 1 : 0;
  mn[a] = flag;
  __syncthreads();
  for (int off = 1; off < RMAX; off <<= 1) {
    int v = mn[a];
    int add = (a >= off) ? mn[a - off] : 0;
    __syncthreads();
    mn[a] = v + add;
    __syncthreads();
  }
  clab[a] = mn[lbl[a]] - 1;
}

// per-point labels; collect border (non-core) points into a compact list
__global__ __launch_bounds__(256) void k_labels(const int* __restrict__ labL,
                                                const int* __restrict__ clab,
                                                int* __restrict__ labArr,
                                                int* __restrict__ blist,
                                                int* __restrict__ bcount,
                                                float* __restrict__ out) {
  int i = blockIdx.x * blockDim.x + threadIdx.x;
  if (i >= NPTS) return;
  int a = labL[i];
  if (a >= 0) {
    int lab = clab[a];
    labArr[i] = lab;
    out[i] = (float)lab;
  } else {
    labArr[i] = BIGL;
    out[i] = -1.0f;
    int pos = atomicAdd(bcount, 1);
    blist[pos] = i;
  }
}

// one block per border point: min cluster id over core neighbors (bitmap scan)
__global__ __launch_bounds__(FT) void k_border(const unsigned int* __restrict__ adj,
                                               const unsigned int* __restrict__ cb32,
                                               const int* __restrict__ labArr,
                                               const int* __restrict__ blist,
                                               const int* __restrict__ bcount,
                                               float* __restrict__ out) {
  __shared__ unsigned int cb[NW];
  __shared__ int wm[FT / 64];
  int t = threadIdx.x;
  for (int w = t; w < NW; w += FT) cb[w] = cb32[w];
  __syncthreads();
  int count = *bcount;
  for (int k = blockIdx.x; k < count; k += gridDim.x) {
    int p = blist[k];
    const unsigned int* row = adj + (size_t)p * NW;
    int m = BIGL;
    for (int w = t; w < NW; w += FT) {
      unsigned int x = row[w] & cb[w];
      while (x) {
        int b = __ffs(x) - 1; x &= x - 1;
        m = min(m, labArr[(w << 5) + b]);
      }
    }
#pragma unroll
    for (int off = 32; off >= 1; off >>= 1) m = min(m, __shfl_xor(m, off, 64));
    if ((t & 63) == 0) wm[t >> 6] = m;
    __syncthreads();
    if (t == 0) {
      int mm = min(wm[0], wm[1]);
      out[p] = (mm < BIGL) ? (float)mm : -1.0f;
    }
    __syncthreads();
  }
}

// ---------------- launch ----------------

extern "C" void kernel_launch(void* const* d_in, const int* in_sizes, int n_in,
                              void* d_out, int out_size, void* d_ws, size_t ws_size,
                              hipStream_t stream) {
  const float* X = (const float*)d_in[0];
  float* out = (float*)d_out;

  char* ws = (char*)d_ws;
  unsigned int* adj = (unsigned int*)ws;                     // 18,874,368 B
  size_t off = (size_t)NPTS * NW * 4;
  int* density = (int*)(ws + off);           off += 4 * NPTS;
  int* hook    = (int*)(ws + off);           off += 4 * NPTS;
  int* L0      = (int*)(ws + off);           off += 4 * NPTS;   // -> labArr
  int* labL    = (int*)(ws + off);           off += 4 * NPTS;
  int* blist   = (int*)(ws + off);           off += 4 * NPTS;
  unsigned long long* corebm = (unsigned long long*)(ws + off); off += 2048;
  unsigned int* bm  = (unsigned int*)(ws + off); off += 4 * RMAX * W;
  int* clab    = (int*)(ws + off);           off += 4 * RMAX;
  int* Rptr    = (int*)(ws + off);
  int* bcount  = Rptr + 1;
  int* labArr  = L0;   // L0 dead after k_rid

  hipMemsetAsync(density, 0, 4 * NPTS, stream);

  dim3 gridA(ANIB, ANJB);   // 24 x 48 = 1152 blocks

  k_adj<<<gridA, ATHR, 0, stream>>>(X, adj, density);
  k_core<<<NIB1, 256, 0, stream>>>(density, corebm, bm);
  k_hookbm<<<NIB1, 256, 0, stream>>>(adj, (const unsigned int*)corebm, hook);
  k_compress<<<NIB1, 256, 0, stream>>>(density, hook, L0);
  k_rid<<<1, 1024, 0, stream>>>(density, L0, Rptr, labL, bcount);
  k_fillbm<<<FBGRID, FB, 0, stream>>>(adj, (const unsigned int*)corebm, labL, bm);
  k_cc<<<1, RMAX, 0, stream>>>(bm, Rptr, clab);
  k_labels<<<NIB1, 256, 0, stream>>>(labL, clab, labArr, blist, bcount, out);
  k_border<<<256, FT, 0, stream>>>(adj, (const unsigned int*)corebm, labArr, blist, bcount, out);
}

// Round 10
// 228.193 us; speedup vs baseline: 1.3174x; 1.0531x over previous
//
#include <hip/hip_runtime.h>

#define NPTS 12288
#define DIMS 8
#define EPS2 0.25f
#define MINS 5
#define NIB1 (NPTS / 256)      // 48
#define NW   (NPTS / 32)       // 384 words per adjacency row
#define SENT NPTS
#define RMAX 512               // max contracted labels (R~120 measured OK)
#define W    (RMAX / 32)       // 16 words per contracted-bitmap row
#define BIGL 0x3fffffff
#define FT   128               // threads for border kernel
#define FB   256               // threads for fillbm
#define FBGRID 256             // blocks for fillbm -> 1024 waves

// k_adj geometry: 256 thr x 2 rows = 512 rows/block; j-chunk 256 = 8 words = 32B
// grid 24x48 = 1152 blocks x 4 waves = 4608 waves = 4.5/SIMD (latency hiding)
#define ATHR 256
#define AROWS 2
#define ATI  (ATHR * AROWS)    // 512
#define ANIB (NPTS / ATI)      // 24
#define ANJB 48
#define AJC  (NPTS / ANJB)     // 256
#define AWCH (AJC / 32)        // 8

typedef float v2f __attribute__((ext_vector_type(2)));

// packed-fp32 distance: 1 pk_mul + 3 pk_fma + hadd; same threshold semantics
__device__ __forceinline__ float dot8(const v2f* xi, const float4& a, const float4& b) {
  v2f y0 = {a.x, a.y}, y1 = {a.z, a.w}, y2 = {b.x, b.y}, y3 = {b.z, b.w};
  v2f d = xi[0] * y0;
  d = __builtin_elementwise_fma(xi[1], y1, d);
  d = __builtin_elementwise_fma(xi[2], y2, d);
  d = __builtin_elementwise_fma(xi[3], y3, d);
  return d.x + d.y;
}

// ---------------- kernels ----------------

// the ONLY N^2 distance pass; acc in registers (8 words/row), 32B burst store,
// fused density popcount.
__global__ __launch_bounds__(ATHR) void k_adj(const float* __restrict__ X,
                                              unsigned int* __restrict__ adj,
                                              int* __restrict__ density) {
  __shared__ float4 xs[AJC][2];
  __shared__ float sqs[AJC];
  int t = threadIdx.x;
  int j0 = blockIdx.y * AJC;
  {
    int j = j0 + t;
    float4 a = ((const float4*)X)[j * 2];
    float4 b = ((const float4*)X)[j * 2 + 1];
    xs[t][0] = a; xs[t][1] = b;
    float sv = 0.f;
    sv = fmaf(a.x, a.x, sv); sv = fmaf(a.y, a.y, sv); sv = fmaf(a.z, a.z, sv); sv = fmaf(a.w, a.w, sv);
    sv = fmaf(b.x, b.x, sv); sv = fmaf(b.y, b.y, sv); sv = fmaf(b.z, b.z, sv); sv = fmaf(b.w, b.w, sv);
    sqs[t] = sv;
  }
  int i0 = blockIdx.x * ATI + t, i1 = i0 + ATHR;
  v2f xi0[4], xi1[4];
  {
    float4 a0 = ((const float4*)X)[i0 * 2], b0v = ((const float4*)X)[i0 * 2 + 1];
    float4 a1 = ((const float4*)X)[i1 * 2], b1v = ((const float4*)X)[i1 * 2 + 1];
    xi0[0] = (v2f){a0.x, a0.y}; xi0[1] = (v2f){a0.z, a0.w};
    xi0[2] = (v2f){b0v.x, b0v.y}; xi0[3] = (v2f){b0v.z, b0v.w};
    xi1[0] = (v2f){a1.x, a1.y}; xi1[1] = (v2f){a1.z, a1.w};
    xi1[2] = (v2f){b1v.x, b1v.y}; xi1[3] = (v2f){b1v.z, b1v.w};
  }
  float sq0 = 0.f, sq1 = 0.f;
#pragma unroll
  for (int q = 0; q < 4; q++) {
    v2f p0 = xi0[q] * xi0[q], p1 = xi1[q] * xi1[q];
    sq0 += p0.x + p0.y; sq1 += p1.x + p1.y;
  }
  __syncthreads();
  unsigned int acc0[AWCH], acc1[AWCH];
#pragma unroll
  for (int w = 0; w < AWCH; w++) {   // unrolled: constant acc indices
    unsigned int b0 = 0u, b1 = 0u;
#pragma unroll 4
    for (int bit = 0; bit < 32; bit++) {
      int jj = (w << 5) + bit;
      float4 xa = xs[jj][0], xb = xs[jj][1];
      float sj = sqs[jj];
      unsigned int m = 1u << bit;
      float d20 = (sq0 + sj) - 2.0f * dot8(xi0, xa, xb);
      float d21 = (sq1 + sj) - 2.0f * dot8(xi1, xa, xb);
      if (d20 <= EPS2) b0 |= m;
      if (d21 <= EPS2) b1 |= m;
    }
    acc0[w] = b0; acc1[w] = b1;
  }
  uint4* dst0 = (uint4*)(adj + (size_t)i0 * NW + blockIdx.y * AWCH);
  uint4* dst1 = (uint4*)(adj + (size_t)i1 * NW + blockIdx.y * AWCH);
  dst0[0] = make_uint4(acc0[0], acc0[1], acc0[2], acc0[3]);
  dst0[1] = make_uint4(acc0[4], acc0[5], acc0[6], acc0[7]);
  dst1[0] = make_uint4(acc1[0], acc1[1], acc1[2], acc1[3]);
  dst1[1] = make_uint4(acc1[4], acc1[5], acc1[6], acc1[7]);
  int pc0 = 0, pc1 = 0;
#pragma unroll
  for (int w = 0; w < AWCH; w++) { pc0 += __popc(acc0[w]); pc1 += __popc(acc1[w]); }
  atomicAdd(&density[i0], pc0);
  atomicAdd(&density[i1], pc1);
}

// corebm via ballot; block 0 zeroes the contracted bitmap
__global__ __launch_bounds__(256) void k_core(const int* __restrict__ density,
                                              unsigned long long* __restrict__ corebm,
                                              unsigned int* __restrict__ bm) {
  int t = threadIdx.x;
  if (blockIdx.x == 0) {
#pragma unroll
    for (int q = 0; q < RMAX * W / 256; q++) bm[t + q * 256] = 0u;
  }
  int i = blockIdx.x * 256 + t;
  unsigned long long m = __ballot(density[i] >= MINS);
  if ((t & 63) == 0) corebm[i >> 6] = m;
}

// hook[i] = min(i, first core neighbor with j < i)  (j > i can't lower the min)
__global__ __launch_bounds__(256) void k_hookbm(const unsigned int* __restrict__ adj,
                                                const unsigned int* __restrict__ cb32,
                                                int* __restrict__ hook) {
  __shared__ unsigned int cb[NW];
  int t = threadIdx.x;
  for (int w = t; w < NW; w += 256) cb[w] = cb32[w];
  __syncthreads();
  int i = blockIdx.x * 256 + t;
  const unsigned int* row = adj + (size_t)i * NW;
  int wi = i >> 5;
  int m = i;
  for (int w = 0; w <= wi; w++) {
    unsigned int x = row[w] & cb[w];
    if (w == wi) x &= (1u << (i & 31)) - 1;   // bits strictly below i
    if (x) { m = (w << 5) + __ffs(x) - 1; break; }  // first hit = min
  }
  hook[i] = m;
}

// root ranks in LDS + hook-chase (fused compress) + labL; 1024 threads.
__global__ __launch_bounds__(1024) void k_rid(const int* __restrict__ density,
                                              const int* __restrict__ hook,
                                              int* __restrict__ Rptr,
                                              int* __restrict__ labL,
                                              int* __restrict__ bcount) {
  __shared__ unsigned short ridS[NPTS];   // 24 KB: rank of each root index
  __shared__ int wsum[16];
  int t = threadIdx.x;
  int lane = t & 63, wid = t >> 6;
  const int SEG = NPTS / 1024;  // 12
  int base = t * SEG;
  int flags = 0;
  int s = 0;
#pragma unroll
  for (int k = 0; k < SEG; k++) {
    int i = base + k;
    int f = (density[i] >= MINS && hook[i] == i) ? 1 : 0;   // root test
    flags |= f << k;
    s += f;
  }
  int segsum = s;
#pragma unroll
  for (int off = 1; off < 64; off <<= 1) {
    int n = __shfl_up(s, off, 64);
    if (lane >= off) s += n;
  }
  if (lane == 63) wsum[wid] = s;
  __syncthreads();
  int woff = 0;
  for (int w = 0; w < wid; w++) woff += wsum[w];
  int run = woff + s - segsum;
#pragma unroll
  for (int k = 0; k < SEG; k++) {
    ridS[base + k] = (unsigned short)run;
    run += (flags >> k) & 1;
  }
  if (t == 1023) *Rptr = run;
  if (t == 0) *bcount = 0;
  __syncthreads();
  for (int k = 0; k < SEG; k++) {
    int i = base + k;
    int lab = -1;
    if (density[i] >= MINS) {
      int v = i, h = hook[v];                 // chase static forest (decreasing)
      while (h != v) { v = h; h = hook[v]; }
      lab = min((int)ridS[v], RMAX - 1);
    }
    labL[i] = lab;
  }
}

// crossing-label edges -> contracted adjacency. Wave-per-row, j>i only;
// labels from LDS; hot atomics in LDS; batched merge.
__global__ __launch_bounds__(FB) void k_fillbm(const unsigned int* __restrict__ adj,
                                               const unsigned int* __restrict__ cb32,
                                               const int* __restrict__ labL,
                                               unsigned int* __restrict__ bm) {
  __shared__ unsigned int bmL[RMAX * W];       // 32 KB private bitmap
  __shared__ unsigned short labS[NPTS];        // 24 KB labels (+1, 0 = non-core)
  __shared__ unsigned int cb[NW];              // 1.5 KB core bitmap
  int t = threadIdx.x;
  for (int q = t; q < RMAX * W; q += FB) bmL[q] = 0u;
  for (int q = t; q < NPTS; q += FB) labS[q] = (unsigned short)(labL[q] + 1);
  for (int w = t; w < NW; w += FB) cb[w] = cb32[w];
  __syncthreads();
  int lane = t & 63, wv = t >> 6;              // 4 waves per block
  int gw = blockIdx.x * 4 + wv;                // global wave id 0..1023
  for (int i = gw; i < NPTS; i += 4 * FBGRID) {
    int a0 = (int)labS[i] - 1;
    if (a0 < 0) continue;                      // wave-uniform
    const unsigned int* row = adj + (size_t)i * NW;
    int wi = i >> 5;
    for (int w = wi + lane; w < NW; w += 64) {
      unsigned int x = row[w] & cb[w];
      if (w == wi) x &= (0xFFFFFFFEu << (i & 31));   // bits strictly > i
      while (x) {
        int b = __ffs(x) - 1; x &= x - 1;
        int lj = (int)labS[(w << 5) + b] - 1;
        if (lj != a0) {
          atomicOr(&bmL[a0 * W + (lj >> 5)], 1u << (lj & 31));
          atomicOr(&bmL[lj * W + (a0 >> 5)], 1u << (a0 & 31));
        }
      }
    }
  }
  __syncthreads();
  for (int q = t; q < RMAX * W; q += FB) {
    unsigned int v = bmL[q];
    if (v) atomicOr(&bm[q], v);
  }
}

// connected components of the contracted graph (single block, LDS) + rank ids
__global__ __launch_bounds__(RMAX) void k_cc(const unsigned int* __restrict__ bm,
                                             const int* __restrict__ Rptr,
                                             int* __restrict__ clab) {
  __shared__ int lbl[RMAX];
  __shared__ int mn[RMAX];
  __shared__ int chg, cmp;
  int a = threadIdx.x;
  int R = *Rptr; if (R > RMAX) R = RMAX;
  lbl[a] = a;
  __syncthreads();
  while (true) {
    int m = lbl[a];
    if (a < R) {
      const unsigned int* row = bm + a * W;
#pragma unroll
      for (int w = 0; w < W; w++) {
        unsigned int bits = row[w];
        while (bits) {
          int b = __ffs(bits) - 1;
          bits &= bits - 1;
          m = min(m, lbl[(w << 5) + b]);
        }
      }
    }
    mn[a] = m;
    if (a == 0) chg = 0;
    __syncthreads();
    int l = lbl[a];
    if (m < l) { atomicMin(&lbl[l], m); atomicMin(&lbl[a], m); chg = 1; }
    __syncthreads();
    while (true) {
      if (a == 0) cmp = 0;
      __syncthreads();
      int nl = lbl[lbl[a]];
      __syncthreads();
      if (nl < lbl[a]) { lbl[a] = nl; cmp = 1; }
      __syncthreads();
      if (!cmp) break;
    }
    if (!chg) break;
    __syncthreads();
  }
  int flag = (a < R && lbl[a] == a) ? 1 : 0;
  mn[a] = flag;
  __syncthreads();
  for (int off = 1; off < RMAX; off <<= 1) {
    int v = mn[a];
    int add = (a >= off) ? mn[a - off] : 0;
    __syncthreads();
    mn[a] = v + add;
    __syncthreads();
  }
  clab[a] = mn[lbl[a]] - 1;
}

// per-point labels; collect border (non-core) points into a compact list
__global__ __launch_bounds__(256) void k_labels(const int* __restrict__ labL,
                                                const int* __restrict__ clab,
                                                int* __restrict__ labArr,
                                                int* __restrict__ blist,
                                                int* __restrict__ bcount,
                                                float* __restrict__ out) {
  int i = blockIdx.x * blockDim.x + threadIdx.x;
  if (i >= NPTS) return;
  int a = labL[i];
  if (a >= 0) {
    int lab = clab[a];
    labArr[i] = lab;
    out[i] = (float)lab;
  } else {
    labArr[i] = BIGL;
    out[i] = -1.0f;
    int pos = atomicAdd(bcount, 1);
    blist[pos] = i;
  }
}

// one block per border point: min cluster id over core neighbors (bitmap scan)
__global__ __launch_bounds__(FT) void k_border(const unsigned int* __restrict__ adj,
                                               const unsigned int* __restrict__ cb32,
                                               const int* __restrict__ labArr,
                                               const int* __restrict__ blist,
                                               const int* __restrict__ bcount,
                                               float* __restrict__ out) {
  __shared__ unsigned int cb[NW];
  __shared__ int wm[FT / 64];
  int t = threadIdx.x;
  for (int w = t; w < NW; w += FT) cb[w] = cb32[w];
  __syncthreads();
  int count = *bcount;
  for (int k = blockIdx.x; k < count; k += gridDim.x) {
    int p = blist[k];
    const unsigned int* row = adj + (size_t)p * NW;
    int m = BIGL;
    for (int w = t; w < NW; w += FT) {
      unsigned int x = row[w] & cb[w];
      while (x) {
        int b = __ffs(x) - 1; x &= x - 1;
        m = min(m, labArr[(w << 5) + b]);
      }
    }
#pragma unroll
    for (int off = 32; off >= 1; off >>= 1) m = min(m, __shfl_xor(m, off, 64));
    if ((t & 63) == 0) wm[t >> 6] = m;
    __syncthreads();
    if (t == 0) {
      int mm = min(wm[0], wm[1]);
      out[p] = (mm < BIGL) ? (float)mm : -1.0f;
    }
    __syncthreads();
  }
}

// ---------------- launch ----------------

extern "C" void kernel_launch(void* const* d_in, const int* in_sizes, int n_in,
                              void* d_out, int out_size, void* d_ws, size_t ws_size,
                              hipStream_t stream) {
  const float* X = (const float*)d_in[0];
  float* out = (float*)d_out;

  char* ws = (char*)d_ws;
  unsigned int* adj = (unsigned int*)ws;                     // 18,874,368 B
  size_t off = (size_t)NPTS * NW * 4;
  int* density = (int*)(ws + off);           off += 4 * NPTS;
  int* hook    = (int*)(ws + off);           off += 4 * NPTS;
  int* labL    = (int*)(ws + off);           off += 4 * NPTS;
  int* labArr  = (int*)(ws + off);           off += 4 * NPTS;
  int* blist   = (int*)(ws + off);           off += 4 * NPTS;
  unsigned long long* corebm = (unsigned long long*)(ws + off); off += 2048;
  unsigned int* bm  = (unsigned int*)(ws + off); off += 4 * RMAX * W;
  int* clab    = (int*)(ws + off);           off += 4 * RMAX;
  int* Rptr    = (int*)(ws + off);
  int* bcount  = Rptr + 1;

  hipMemsetAsync(density, 0, 4 * NPTS, stream);

  dim3 gridA(ANIB, ANJB);   // 24 x 48 = 1152 blocks x 4 waves

  k_adj<<<gridA, ATHR, 0, stream>>>(X, adj, density);
  k_core<<<NIB1, 256, 0, stream>>>(density, corebm, bm);
  k_hookbm<<<NIB1, 256, 0, stream>>>(adj, (const unsigned int*)corebm, hook);
  k_rid<<<1, 1024, 0, stream>>>(density, hook, Rptr, labL, bcount);
  k_fillbm<<<FBGRID, FB, 0, stream>>>(adj, (const unsigned int*)corebm, labL, bm);
  k_cc<<<1, RMAX, 0, stream>>>(bm, Rptr, clab);
  k_labels<<<NIB1, 256, 0, stream>>>(labL, clab, labArr, blist, bcount, out);
  k_border<<<256, FT, 0, stream>>>(adj, (const unsigned int*)corebm, labArr, blist, bcount, out);
}